// Round 1
// baseline (897.777 us; speedup 1.0000x reference)
//
#include <hip/hip_runtime.h>

#define DEV __device__ __forceinline__

typedef __attribute__((ext_vector_type(8))) short short8;
typedef __attribute__((ext_vector_type(4))) float f32x4;

// ---------- helpers ----------
DEV unsigned short f2bf(float f) {
  unsigned u = __builtin_bit_cast(unsigned, f);
  u += 0x7fff + ((u >> 16) & 1);   // RNE
  return (unsigned short)(u >> 16);
}

DEV void gload_lds16(const void* g, void* l) {
  __builtin_amdgcn_global_load_lds(
      (const __attribute__((address_space(1))) void*)g,
      (__attribute__((address_space(3))) void*)l, 16, 0, 0);
}

#if __has_builtin(__builtin_amdgcn_exp2f)
#define EXP2F(x) __builtin_amdgcn_exp2f(x)
#else
#define EXP2F(x) exp2f(x)
#endif

#define MFMA16(a, b, c) __builtin_amdgcn_mfma_f32_16x16x32_bf16((a), (b), (c), 0, 0, 0)

// ---------- fp32 -> bf16 conversion ----------
__global__ void cvt_f32_bf16(const float* __restrict__ in, unsigned short* __restrict__ out, int n4) {
  int i = blockIdx.x * blockDim.x + threadIdx.x;
  int stride = gridDim.x * blockDim.x;
  for (; i < n4; i += stride) {
    float4 v = ((const float4*)in)[i];
    ushort4 o;
    o.x = f2bf(v.x); o.y = f2bf(v.y); o.z = f2bf(v.z); o.w = f2bf(v.w);
    ((ushort4*)out)[i] = o;
  }
}

// ---------- GEMM: C[m,n] = sum_k A[m,k] * B[n,k]   (NT, K=1024) ----------
// MODE 0: bf16 row-major [M][1024]; MODE 1: bf16 Vt layout [(b*16+h)*64+d][2048]; MODE 2: fp32 row-major
#define GK 1024
template <int MODE>
__global__ __launch_bounds__(256) void gemm_bt(const unsigned short* __restrict__ A,
                                               const unsigned short* __restrict__ Bw,
                                               void* __restrict__ Cout) {
  __shared__ unsigned short Ash[128 * 32];
  __shared__ unsigned short Bsh[128 * 32];
  const int tid = threadIdx.x;
  const int lane = tid & 63;
  const int w = tid >> 6;
  const int wm = w >> 1, wn = w & 1;
  const int l15 = lane & 15, l4 = lane >> 4;
  const int row0 = blockIdx.y * 128;
  const int col0 = blockIdx.x * 128;

  f32x4 acc[4][4] = {};

  for (int kt = 0; kt < GK; kt += 32) {
    __syncthreads();
#pragma unroll
    for (int c = 0; c < 2; ++c) {
      int o = c * 4096 + tid * 16;              // linear byte offset in 8KB tile
      int ldsoff = c * 4096 + w * 1024;         // wave-uniform LDS base
      int row = o >> 6, colb = o & 63;
      gload_lds16((const char*)A + (size_t)(row0 + row) * 2048 + kt * 2 + colb,
                  (char*)Ash + ldsoff);
      gload_lds16((const char*)Bw + (size_t)(col0 + row) * 2048 + kt * 2 + colb,
                  (char*)Bsh + ldsoff);
    }
    __syncthreads();
    short8 af[4], bf[4];
#pragma unroll
    for (int m = 0; m < 4; ++m)
      af[m] = *(const short8*)((const char*)Ash + (wm * 64 + m * 16 + l15) * 64 + l4 * 16);
#pragma unroll
    for (int n = 0; n < 4; ++n)
      bf[n] = *(const short8*)((const char*)Bsh + (wn * 64 + n * 16 + l15) * 64 + l4 * 16);
#pragma unroll
    for (int m = 0; m < 4; ++m)
#pragma unroll
      for (int n = 0; n < 4; ++n)
        acc[m][n] = MFMA16(af[m], bf[n], acc[m][n]);
  }

#pragma unroll
  for (int m = 0; m < 4; ++m)
#pragma unroll
    for (int n = 0; n < 4; ++n)
#pragma unroll
      for (int r = 0; r < 4; ++r) {
        int mrow = row0 + wm * 64 + m * 16 + l4 * 4 + r;   // C/D: row=(lane>>4)*4+reg
        int ncol = col0 + wn * 64 + n * 16 + l15;          //      col=lane&15
        float v = acc[m][n][r];
        if (MODE == 0) {
          ((unsigned short*)Cout)[(size_t)mrow * 1024 + ncol] = f2bf(v);
        } else if (MODE == 1) {
          int b = mrow >> 11, s = mrow & 2047, h = ncol >> 6, d = ncol & 63;
          ((unsigned short*)Cout)[((size_t)((b * 16 + h) * 64 + d)) * 2048 + s] = f2bf(v);
        } else {
          ((float*)Cout)[(size_t)mrow * 1024 + ncol] = v;
        }
      }
}

// ---------- fused causal attention ----------
// grid = (S/64, B*H); block = 256 (4 waves). Wave w: 16 q-rows [qt*64+w*16, +16).
// Swapped QK^T: T[j][q] = sum_k K[j,k] Q[q,k]; lane owns q = q0+(lane&15), 16 j's per tile.
__global__ __launch_bounds__(256) void attn_fused(const unsigned short* __restrict__ Q,
                                                  const unsigned short* __restrict__ Kb,
                                                  const unsigned short* __restrict__ Vt,
                                                  float* __restrict__ attn,
                                                  unsigned short* __restrict__ O) {
  __shared__ unsigned short P_lds[4][16][72];   // per-wave 16x64 bf16 P, padded to 72
  const int tid = threadIdx.x, lane = tid & 63, w = tid >> 6;
  const int l15 = lane & 15, l4 = lane >> 4;
  const int qt = blockIdx.x;
  const int bh = blockIdx.y;
  const int b = bh >> 4, h = bh & 15;
  const int q0 = qt * 64 + w * 16;
  const int myq = q0 + l15;

  const size_t qk_base = ((size_t)b * 2048) * 1024 + h * 64;
  const unsigned short* Qp = Q + qk_base;       // row s: s*1024 + k
  const unsigned short* Kp = Kb + qk_base;
  const unsigned short* Vp = Vt + (size_t)bh * 64 * 2048;  // row d: d*2048 + j
  float* Ap = attn + (size_t)bh * 2048 * 2048;

  // Q fragments (B-operand): lane holds Q[q0+l15][l4*8 .. +8] per 32-k step
  short8 qf[2];
  {
    const char* qrow = (const char*)(Qp + (size_t)(q0 + l15) * 1024);
    qf[0] = *(const short8*)(qrow + (l4 * 8) * 2);
    qf[1] = *(const short8*)(qrow + (32 + l4 * 8) * 2);
  }

  const float scale = 0.125f;                 // 1/sqrt(64)
  const float LOG2E = 1.4426950408889634f;
  float m_run = -INFINITY, l_run = 0.f;

  // ---- PASS A: softmax stats ----
  for (int jt = 0; jt <= qt; ++jt) {
    const int jbase = jt * 64;
    const bool diag = (jt == qt);
    f32x4 t[4];
#pragma unroll
    for (int jb = 0; jb < 4; ++jb) {
      const char* krow = (const char*)(Kp + (size_t)(jbase + jb * 16 + l15) * 1024);
      short8 k0 = *(const short8*)(krow + (l4 * 8) * 2);
      short8 k1 = *(const short8*)(krow + (32 + l4 * 8) * 2);
      f32x4 a = {};
      a = MFMA16(k0, qf[0], a);
      a = MFMA16(k1, qf[1], a);
      t[jb] = a;
    }
    float s[16];
    float tm = -INFINITY;
#pragma unroll
    for (int jb = 0; jb < 4; ++jb)
#pragma unroll
      for (int r = 0; r < 4; ++r) {
        int j = jbase + jb * 16 + l4 * 4 + r;   // C/D: row(j)=(lane>>4)*4+reg
        float v = t[jb][r] * scale;
        if (diag && j > myq) v = -INFINITY;
        s[jb * 4 + r] = v;
        tm = fmaxf(tm, v);
      }
    tm = fmaxf(tm, __shfl_xor(tm, 16));
    tm = fmaxf(tm, __shfl_xor(tm, 32));
    float m_new = fmaxf(m_run, tm);
    float sum = 0.f;
#pragma unroll
    for (int i = 0; i < 16; ++i) sum += EXP2F((s[i] - m_new) * LOG2E);
    sum += __shfl_xor(sum, 16);
    sum += __shfl_xor(sum, 32);
    l_run = l_run * EXP2F((m_run - m_new) * LOG2E) + sum;
    m_run = m_new;
  }
  const float inv_l = 1.f / l_run;

  // ---- PASS B: write attn + PV ----
  f32x4 oacc[4] = {};
  for (int jt = 0; jt <= qt; ++jt) {
    const int jbase = jt * 64;
    const bool diag = (jt == qt);
    f32x4 t[4];
#pragma unroll
    for (int jb = 0; jb < 4; ++jb) {
      const char* krow = (const char*)(Kp + (size_t)(jbase + jb * 16 + l15) * 1024);
      short8 k0 = *(const short8*)(krow + (l4 * 8) * 2);
      short8 k1 = *(const short8*)(krow + (32 + l4 * 8) * 2);
      f32x4 a = {};
      a = MFMA16(k0, qf[0], a);
      a = MFMA16(k1, qf[1], a);
      t[jb] = a;
    }
    float p[16];
#pragma unroll
    for (int jb = 0; jb < 4; ++jb)
#pragma unroll
      for (int r = 0; r < 4; ++r) {
        int j = jbase + jb * 16 + l4 * 4 + r;
        float v = t[jb][r] * scale;
        if (diag && j > myq) v = -INFINITY;
        p[jb * 4 + r] = EXP2F((v - m_run) * LOG2E) * inv_l;  // exp(-inf)=0 handles mask
      }
    // write normalized attn (fp32)
#pragma unroll
    for (int jb = 0; jb < 4; ++jb) {
      f32x4 pv = {p[jb * 4], p[jb * 4 + 1], p[jb * 4 + 2], p[jb * 4 + 3]};
      *(f32x4*)(Ap + (size_t)myq * 2048 + jbase + jb * 16 + l4 * 4) = pv;
    }
    // P -> LDS (bf16), row q=l15, cols jb*16+l4*4..+4
    char* pbase = (char*)&P_lds[w][0][0];
#pragma unroll
    for (int jb = 0; jb < 4; ++jb) {
      unsigned u0 = f2bf(p[jb * 4]) | ((unsigned)f2bf(p[jb * 4 + 1]) << 16);
      unsigned u1 = f2bf(p[jb * 4 + 2]) | ((unsigned)f2bf(p[jb * 4 + 3]) << 16);
      uint2 uu; uu.x = u0; uu.y = u1;
      *(uint2*)(pbase + l15 * 144 + (jb * 16 + l4 * 4) * 2) = uu;
    }
    // PV: A-frag from P_lds (row=l15, k=l4*8), B-frag from Vt rows (d=db*16+l15, j contiguous)
    short8 pa0 = *(const short8*)(pbase + l15 * 144 + (l4 * 8) * 2);
    short8 pa1 = *(const short8*)(pbase + l15 * 144 + 64 + (l4 * 8) * 2);
#pragma unroll
    for (int db = 0; db < 4; ++db) {
      const char* vrow = (const char*)(Vp + (size_t)(db * 16 + l15) * 2048);
      short8 v0 = *(const short8*)(vrow + (jbase + l4 * 8) * 2);
      short8 v1 = *(const short8*)(vrow + (jbase + 32 + l4 * 8) * 2);
      oacc[db] = MFMA16(pa0, v0, oacc[db]);
      oacc[db] = MFMA16(pa1, v1, oacc[db]);
    }
  }

  // zero-fill fully-masked tiles
  for (int jt = qt + 1; jt < 32; ++jt) {
    const int jbase = jt * 64;
    f32x4 z = {};
#pragma unroll
    for (int jb = 0; jb < 4; ++jb)
      *(f32x4*)(Ap + (size_t)myq * 2048 + jbase + jb * 16 + l4 * 4) = z;
  }

  // write O (bf16): D layout row q=(l4*4+r), col d=db*16+l15
#pragma unroll
  for (int db = 0; db < 4; ++db)
#pragma unroll
    for (int r = 0; r < 4; ++r) {
      int q = q0 + l4 * 4 + r;
      int d = db * 16 + l15;
      O[((size_t)b * 2048 + q) * 1024 + h * 64 + d] = f2bf(oacc[db][r]);
    }
}

// ---------- launch ----------
extern "C" void kernel_launch(void* const* d_in, const int* in_sizes, int n_in,
                              void* d_out, int out_size, void* d_ws, size_t ws_size,
                              hipStream_t stream) {
  const float* x  = (const float*)d_in[0];
  // d_in[1] = mask (causal, recomputed analytically)
  const float* wq = (const float*)d_in[2];
  const float* wk = (const float*)d_in[3];
  const float* wv = (const float*)d_in[4];
  const float* wo = (const float*)d_in[5];

  float* out  = (float*)d_out;
  float* attn = out + (size_t)8192 * 1024;

  char* ws = (char*)d_ws;
  const size_t MB = 1 << 20;
  unsigned short* xb  = (unsigned short*)(ws);
  unsigned short* wqb = (unsigned short*)(ws + 16 * MB);
  unsigned short* wkb = (unsigned short*)(ws + 18 * MB);
  unsigned short* wvb = (unsigned short*)(ws + 20 * MB);
  unsigned short* wob = (unsigned short*)(ws + 22 * MB);
  unsigned short* Qb  = (unsigned short*)(ws + 24 * MB);
  unsigned short* Kb  = (unsigned short*)(ws + 40 * MB);
  unsigned short* Vtb = (unsigned short*)(ws + 56 * MB);
  unsigned short* Ob  = (unsigned short*)(ws + 72 * MB);

  // conversions
  cvt_f32_bf16<<<2048, 256, 0, stream>>>(x, xb, 8192 * 1024 / 4);
  cvt_f32_bf16<<<1024, 256, 0, stream>>>(wq, wqb, 1024 * 1024 / 4);
  cvt_f32_bf16<<<1024, 256, 0, stream>>>(wk, wkb, 1024 * 1024 / 4);
  cvt_f32_bf16<<<1024, 256, 0, stream>>>(wv, wvb, 1024 * 1024 / 4);
  cvt_f32_bf16<<<1024, 256, 0, stream>>>(wo, wob, 1024 * 1024 / 4);

  dim3 ggrid(8, 64);   // N/128, M/128
  gemm_bt<0><<<ggrid, 256, 0, stream>>>(xb, wqb, Qb);
  gemm_bt<0><<<ggrid, 256, 0, stream>>>(xb, wkb, Kb);
  gemm_bt<1><<<ggrid, 256, 0, stream>>>(xb, wvb, Vtb);

  attn_fused<<<dim3(32, 64), 256, 0, stream>>>(Qb, Kb, Vtb, attn, Ob);

  gemm_bt<2><<<ggrid, 256, 0, stream>>>(Ob, wob, out);
}

// Round 3
// 729.144 us; speedup vs baseline: 1.2313x; 1.2313x over previous
//
#include <hip/hip_runtime.h>

#define DEV __device__ __forceinline__

typedef __attribute__((ext_vector_type(8))) short short8;
typedef __attribute__((ext_vector_type(4))) float f32x4;

// ---------- helpers ----------
DEV unsigned short f2bf(float f) {
  unsigned u = __builtin_bit_cast(unsigned, f);
  u += 0x7fff + ((u >> 16) & 1);   // RNE
  return (unsigned short)(u >> 16);
}

DEV void gload_lds16(const void* g, void* l) {
  __builtin_amdgcn_global_load_lds(
      (const __attribute__((address_space(1))) void*)g,
      (__attribute__((address_space(3))) void*)l, 16, 0, 0);
}

#if __has_builtin(__builtin_amdgcn_exp2f)
#define EXP2F(x) __builtin_amdgcn_exp2f(x)
#else
#define EXP2F(x) exp2f(x)
#endif

#define LOG2E 1.4426950408889634f
#define MFMA16(a, b, c) __builtin_amdgcn_mfma_f32_16x16x32_bf16((a), (b), (c), 0, 0, 0)

// ---------- fp32 -> bf16 conversion ----------
__global__ void cvt_f32_bf16(const float* __restrict__ in, unsigned short* __restrict__ out, int n4) {
  int i = blockIdx.x * blockDim.x + threadIdx.x;
  int stride = gridDim.x * blockDim.x;
  for (; i < n4; i += stride) {
    float4 v = ((const float4*)in)[i];
    ushort4 o;
    o.x = f2bf(v.x); o.y = f2bf(v.y); o.z = f2bf(v.z); o.w = f2bf(v.w);
    ((ushort4*)out)[i] = o;
  }
}

// ---------- GEMM: C[m,n] = sum_k A[m,k] * B[n,k]   (NT, K=1024) ----------
// MODE 0: bf16 row-major [M][1024]; MODE 1: bf16 Vt layout [(b*16+h)*64+d][2048]; MODE 2: fp32 row-major
#define GK 1024
template <int MODE>
__global__ __launch_bounds__(256) void gemm_bt(const unsigned short* __restrict__ A,
                                               const unsigned short* __restrict__ Bw,
                                               void* __restrict__ Cout) {
  __shared__ unsigned short Ash[128 * 32];
  __shared__ unsigned short Bsh[128 * 32];
  const int tid = threadIdx.x;
  const int lane = tid & 63;
  const int w = tid >> 6;
  const int wm = w >> 1, wn = w & 1;
  const int l15 = lane & 15, l4 = lane >> 4;
  const int row0 = blockIdx.y * 128;
  const int col0 = blockIdx.x * 128;

  f32x4 acc[4][4] = {};

  for (int kt = 0; kt < GK; kt += 32) {
    __syncthreads();
#pragma unroll
    for (int c = 0; c < 2; ++c) {
      int o = c * 4096 + tid * 16;              // linear byte offset in 8KB tile
      int ldsoff = c * 4096 + w * 1024;         // wave-uniform LDS base
      int row = o >> 6, colb = o & 63;
      gload_lds16((const char*)A + (size_t)(row0 + row) * 2048 + kt * 2 + colb,
                  (char*)Ash + ldsoff);
      gload_lds16((const char*)Bw + (size_t)(col0 + row) * 2048 + kt * 2 + colb,
                  (char*)Bsh + ldsoff);
    }
    __syncthreads();
    short8 af[4], bf[4];
#pragma unroll
    for (int m = 0; m < 4; ++m)
      af[m] = *(const short8*)((const char*)Ash + (wm * 64 + m * 16 + l15) * 64 + l4 * 16);
#pragma unroll
    for (int n = 0; n < 4; ++n)
      bf[n] = *(const short8*)((const char*)Bsh + (wn * 64 + n * 16 + l15) * 64 + l4 * 16);
#pragma unroll
    for (int m = 0; m < 4; ++m)
#pragma unroll
      for (int n = 0; n < 4; ++n)
        acc[m][n] = MFMA16(af[m], bf[n], acc[m][n]);
  }

#pragma unroll
  for (int m = 0; m < 4; ++m)
#pragma unroll
    for (int n = 0; n < 4; ++n)
#pragma unroll
      for (int r = 0; r < 4; ++r) {
        int mrow = row0 + wm * 64 + m * 16 + l4 * 4 + r;   // C/D: row=(lane>>4)*4+reg
        int ncol = col0 + wn * 64 + n * 16 + l15;          //      col=lane&15
        float v = acc[m][n][r];
        if (MODE == 0) {
          ((unsigned short*)Cout)[(size_t)mrow * 1024 + ncol] = f2bf(v);
        } else if (MODE == 1) {
          int b = mrow >> 11, s = mrow & 2047, h = ncol >> 6, d = ncol & 63;
          ((unsigned short*)Cout)[((size_t)((b * 16 + h) * 64 + d)) * 2048 + s] = f2bf(v);
        } else {
          ((float*)Cout)[(size_t)mrow * 1024 + ncol] = v;
        }
      }
}

// ---------- fused causal attention v3 ----------
// v1's replay-stable inner code, wrapped in a diagonal-pairing loop for load balance.
// grid = (16, B*H); block = 256 (4 waves). Block pr handles q-tiles {pr, 31-pr}
// (33 jt-iters per pass regardless of pr -> perfect static balance).
__global__ __launch_bounds__(256) void attn_fused(const unsigned short* __restrict__ Q,
                                                  const unsigned short* __restrict__ Kb,
                                                  const unsigned short* __restrict__ Vt,
                                                  float* __restrict__ attn,
                                                  unsigned short* __restrict__ O) {
  __shared__ unsigned short P_lds[4][16][72];   // per-wave 16x64 bf16 P, padded to 72
  const int tid = threadIdx.x, lane = tid & 63, w = tid >> 6;
  const int l15 = lane & 15, l4 = lane >> 4;
  const int pr = blockIdx.x;              // 0..15
  const int bh = blockIdx.y;
  const int b = bh >> 4, h = bh & 15;

  const size_t qk_base = ((size_t)b * 2048) * 1024 + h * 64;
  const unsigned short* Qp = Q + qk_base;       // row s: s*1024 + k
  const unsigned short* Kp = Kb + qk_base;
  const unsigned short* Vp = Vt + (size_t)bh * 64 * 2048;  // row d: d*2048 + j
  float* Ap = attn + (size_t)bh * 2048 * 2048;

  const float scale = 0.125f;                 // 1/sqrt(64)

  for (int t = 0; t < 2; ++t) {
    const int qt = t ? (31 - pr) : pr;
    const int q0 = qt * 64 + w * 16;
    const int myq = q0 + l15;

    // Q fragments (B-operand): lane holds Q[q0+l15][l4*8 .. +8] per 32-k step
    short8 qf[2];
    {
      const char* qrow = (const char*)(Qp + (size_t)(q0 + l15) * 1024);
      qf[0] = *(const short8*)(qrow + (l4 * 8) * 2);
      qf[1] = *(const short8*)(qrow + (32 + l4 * 8) * 2);
    }

    float m_run = -INFINITY, l_run = 0.f;

    // ---- PASS A: softmax stats ----
    for (int jt = 0; jt <= qt; ++jt) {
      const int jbase = jt * 64;
      const bool diag = (jt == qt);
      f32x4 tacc[4];
#pragma unroll
      for (int jb = 0; jb < 4; ++jb) {
        const char* krow = (const char*)(Kp + (size_t)(jbase + jb * 16 + l15) * 1024);
        short8 k0 = *(const short8*)(krow + (l4 * 8) * 2);
        short8 k1 = *(const short8*)(krow + (32 + l4 * 8) * 2);
        f32x4 a = {};
        a = MFMA16(k0, qf[0], a);
        a = MFMA16(k1, qf[1], a);
        tacc[jb] = a;
      }
      float s[16];
      float tm = -INFINITY;
#pragma unroll
      for (int jb = 0; jb < 4; ++jb)
#pragma unroll
        for (int r = 0; r < 4; ++r) {
          int j = jbase + jb * 16 + l4 * 4 + r;   // C/D: row(j)=(lane>>4)*4+reg
          float v = tacc[jb][r] * scale;
          if (diag && j > myq) v = -INFINITY;
          s[jb * 4 + r] = v;
          tm = fmaxf(tm, v);
        }
      tm = fmaxf(tm, __shfl_xor(tm, 16));
      tm = fmaxf(tm, __shfl_xor(tm, 32));
      float m_new = fmaxf(m_run, tm);
      float sum = 0.f;
#pragma unroll
      for (int i = 0; i < 16; ++i) sum += EXP2F((s[i] - m_new) * LOG2E);
      sum += __shfl_xor(sum, 16);
      sum += __shfl_xor(sum, 32);
      l_run = l_run * EXP2F((m_run - m_new) * LOG2E) + sum;
      m_run = m_new;
    }
    const float inv_l = 1.f / l_run;

    // ---- PASS B: write attn + PV ----
    f32x4 oacc[4] = {};
    char* pbase = (char*)&P_lds[w][0][0];
    for (int jt = 0; jt <= qt; ++jt) {
      const int jbase = jt * 64;
      const bool diag = (jt == qt);
      f32x4 tacc[4];
#pragma unroll
      for (int jb = 0; jb < 4; ++jb) {
        const char* krow = (const char*)(Kp + (size_t)(jbase + jb * 16 + l15) * 1024);
        short8 k0 = *(const short8*)(krow + (l4 * 8) * 2);
        short8 k1 = *(const short8*)(krow + (32 + l4 * 8) * 2);
        f32x4 a = {};
        a = MFMA16(k0, qf[0], a);
        a = MFMA16(k1, qf[1], a);
        tacc[jb] = a;
      }
      float p[16];
#pragma unroll
      for (int jb = 0; jb < 4; ++jb)
#pragma unroll
        for (int r = 0; r < 4; ++r) {
          int j = jbase + jb * 16 + l4 * 4 + r;
          float v = tacc[jb][r] * scale;
          if (diag && j > myq) v = -INFINITY;
          p[jb * 4 + r] = EXP2F((v - m_run) * LOG2E) * inv_l;  // exp(-inf)=0 handles mask
        }
      // write normalized attn (fp32)
#pragma unroll
      for (int jb = 0; jb < 4; ++jb) {
        f32x4 pv = {p[jb * 4], p[jb * 4 + 1], p[jb * 4 + 2], p[jb * 4 + 3]};
        *(f32x4*)(Ap + (size_t)myq * 2048 + jbase + jb * 16 + l4 * 4) = pv;
      }
      // P -> LDS (bf16), row q=l15, cols jb*16+l4*4..+4
#pragma unroll
      for (int jb = 0; jb < 4; ++jb) {
        unsigned u0 = f2bf(p[jb * 4]) | ((unsigned)f2bf(p[jb * 4 + 1]) << 16);
        unsigned u1 = f2bf(p[jb * 4 + 2]) | ((unsigned)f2bf(p[jb * 4 + 3]) << 16);
        uint2 uu; uu.x = u0; uu.y = u1;
        *(uint2*)(pbase + l15 * 144 + (jb * 16 + l4 * 4) * 2) = uu;
      }
      // PV: A-frag from P_lds (row=l15, k=l4*8), B-frag from Vt rows (d=db*16+l15, j contiguous)
      short8 pa0 = *(const short8*)(pbase + l15 * 144 + (l4 * 8) * 2);
      short8 pa1 = *(const short8*)(pbase + l15 * 144 + 64 + (l4 * 8) * 2);
#pragma unroll
      for (int db = 0; db < 4; ++db) {
        const char* vrow = (const char*)(Vp + (size_t)(db * 16 + l15) * 2048);
        short8 v0 = *(const short8*)(vrow + (jbase + l4 * 8) * 2);
        short8 v1 = *(const short8*)(vrow + (jbase + 32 + l4 * 8) * 2);
        oacc[db] = MFMA16(pa0, v0, oacc[db]);
        oacc[db] = MFMA16(pa1, v1, oacc[db]);
      }
    }

    // zero-fill fully-masked tiles
    for (int jt = qt + 1; jt < 32; ++jt) {
      const int jbase = jt * 64;
      f32x4 z = {};
#pragma unroll
      for (int jb = 0; jb < 4; ++jb)
        *(f32x4*)(Ap + (size_t)myq * 2048 + jbase + jb * 16 + l4 * 4) = z;
    }

    // write O (bf16): D layout row q=(l4*4+r), col d=db*16+l15
#pragma unroll
    for (int db = 0; db < 4; ++db)
#pragma unroll
      for (int r = 0; r < 4; ++r) {
        int q = q0 + l4 * 4 + r;
        int d = db * 16 + l15;
        O[((size_t)b * 2048 + q) * 1024 + h * 64 + d] = f2bf(oacc[db][r]);
      }
  }
}

// ---------- launch ----------
extern "C" void kernel_launch(void* const* d_in, const int* in_sizes, int n_in,
                              void* d_out, int out_size, void* d_ws, size_t ws_size,
                              hipStream_t stream) {
  const float* x  = (const float*)d_in[0];
  // d_in[1] = mask (causal, recomputed analytically)
  const float* wq = (const float*)d_in[2];
  const float* wk = (const float*)d_in[3];
  const float* wv = (const float*)d_in[4];
  const float* wo = (const float*)d_in[5];

  float* out  = (float*)d_out;
  float* attn = out + (size_t)8192 * 1024;

  char* ws = (char*)d_ws;
  const size_t MB = 1 << 20;
  unsigned short* xb  = (unsigned short*)(ws);
  unsigned short* wqb = (unsigned short*)(ws + 16 * MB);
  unsigned short* wkb = (unsigned short*)(ws + 18 * MB);
  unsigned short* wvb = (unsigned short*)(ws + 20 * MB);
  unsigned short* wob = (unsigned short*)(ws + 22 * MB);
  unsigned short* Qb  = (unsigned short*)(ws + 24 * MB);
  unsigned short* Kb  = (unsigned short*)(ws + 40 * MB);
  unsigned short* Vtb = (unsigned short*)(ws + 56 * MB);
  unsigned short* Ob  = (unsigned short*)(ws + 72 * MB);

  // conversions
  cvt_f32_bf16<<<2048, 256, 0, stream>>>(x, xb, 8192 * 1024 / 4);
  cvt_f32_bf16<<<1024, 256, 0, stream>>>(wq, wqb, 1024 * 1024 / 4);
  cvt_f32_bf16<<<1024, 256, 0, stream>>>(wk, wkb, 1024 * 1024 / 4);
  cvt_f32_bf16<<<1024, 256, 0, stream>>>(wv, wvb, 1024 * 1024 / 4);
  cvt_f32_bf16<<<1024, 256, 0, stream>>>(wo, wob, 1024 * 1024 / 4);

  dim3 ggrid(8, 64);   // N/128, M/128
  gemm_bt<0><<<ggrid, 256, 0, stream>>>(xb, wqb, Qb);
  gemm_bt<0><<<ggrid, 256, 0, stream>>>(xb, wkb, Kb);
  gemm_bt<1><<<ggrid, 256, 0, stream>>>(xb, wvb, Vtb);

  attn_fused<<<dim3(16, 64), 256, 0, stream>>>(Qb, Kb, Vtb, attn, Ob);

  gemm_bt<2><<<ggrid, 256, 0, stream>>>(Ob, wob, out);
}

// Round 4
// 665.065 us; speedup vs baseline: 1.3499x; 1.0964x over previous
//
#include <hip/hip_runtime.h>

#define DEV __device__ __forceinline__

typedef __attribute__((ext_vector_type(8))) short short8;
typedef __attribute__((ext_vector_type(4))) float f32x4;

// ---------- helpers ----------
DEV unsigned short f2bf(float f) {
  unsigned u = __builtin_bit_cast(unsigned, f);
  u += 0x7fff + ((u >> 16) & 1);   // RNE
  return (unsigned short)(u >> 16);
}

DEV void gload_lds16(const void* g, void* l) {
  __builtin_amdgcn_global_load_lds(
      (const __attribute__((address_space(1))) void*)g,
      (__attribute__((address_space(3))) void*)l, 16, 0, 0);
}

#if __has_builtin(__builtin_amdgcn_exp2f)
#define EXP2F(x) __builtin_amdgcn_exp2f(x)
#else
#define EXP2F(x) exp2f(x)
#endif

#define LOG2E 1.4426950408889634f
#define MFMA16(a, b, c) __builtin_amdgcn_mfma_f32_16x16x32_bf16((a), (b), (c), 0, 0, 0)

// ---------- fp32 -> bf16 conversion ----------
__global__ void cvt_f32_bf16(const float* __restrict__ in, unsigned short* __restrict__ out, int n4) {
  int i = blockIdx.x * blockDim.x + threadIdx.x;
  int stride = gridDim.x * blockDim.x;
  for (; i < n4; i += stride) {
    float4 v = ((const float4*)in)[i];
    ushort4 o;
    o.x = f2bf(v.x); o.y = f2bf(v.y); o.z = f2bf(v.z); o.w = f2bf(v.w);
    ((ushort4*)out)[i] = o;
  }
}

// ---------- GEMM: C[m,n] = sum_k A[m,k] * B[n,k]   (NT, K=1024) ----------
// MODE 0: bf16 row-major [M][1024]; MODE 1: bf16 Vt layout [(b*16+h)*64+d][2048]; MODE 2: fp32 row-major
#define GK 1024
template <int MODE>
__global__ __launch_bounds__(256) void gemm_bt(const unsigned short* __restrict__ A,
                                               const unsigned short* __restrict__ Bw,
                                               void* __restrict__ Cout) {
  __shared__ unsigned short Ash[128 * 32];
  __shared__ unsigned short Bsh[128 * 32];
  const int tid = threadIdx.x;
  const int lane = tid & 63;
  const int w = tid >> 6;
  const int wm = w >> 1, wn = w & 1;
  const int l15 = lane & 15, l4 = lane >> 4;
  const int row0 = blockIdx.y * 128;
  const int col0 = blockIdx.x * 128;

  f32x4 acc[4][4] = {};

  for (int kt = 0; kt < GK; kt += 32) {
    __syncthreads();
#pragma unroll
    for (int c = 0; c < 2; ++c) {
      int o = c * 4096 + tid * 16;              // linear byte offset in 8KB tile
      int ldsoff = c * 4096 + w * 1024;         // wave-uniform LDS base
      int row = o >> 6, colb = o & 63;
      gload_lds16((const char*)A + (size_t)(row0 + row) * 2048 + kt * 2 + colb,
                  (char*)Ash + ldsoff);
      gload_lds16((const char*)Bw + (size_t)(col0 + row) * 2048 + kt * 2 + colb,
                  (char*)Bsh + ldsoff);
    }
    __syncthreads();
    short8 af[4], bf[4];
#pragma unroll
    for (int m = 0; m < 4; ++m)
      af[m] = *(const short8*)((const char*)Ash + (wm * 64 + m * 16 + l15) * 64 + l4 * 16);
#pragma unroll
    for (int n = 0; n < 4; ++n)
      bf[n] = *(const short8*)((const char*)Bsh + (wn * 64 + n * 16 + l15) * 64 + l4 * 16);
#pragma unroll
    for (int m = 0; m < 4; ++m)
#pragma unroll
      for (int n = 0; n < 4; ++n)
        acc[m][n] = MFMA16(af[m], bf[n], acc[m][n]);
  }

#pragma unroll
  for (int m = 0; m < 4; ++m)
#pragma unroll
    for (int n = 0; n < 4; ++n)
#pragma unroll
      for (int r = 0; r < 4; ++r) {
        int mrow = row0 + wm * 64 + m * 16 + l4 * 4 + r;   // C/D: row=(lane>>4)*4+reg
        int ncol = col0 + wn * 64 + n * 16 + l15;          //      col=lane&15
        float v = acc[m][n][r];
        if (MODE == 0) {
          ((unsigned short*)Cout)[(size_t)mrow * 1024 + ncol] = f2bf(v);
        } else if (MODE == 1) {
          int b = mrow >> 11, s = mrow & 2047, h = ncol >> 6, d = ncol & 63;
          ((unsigned short*)Cout)[((size_t)((b * 16 + h) * 64 + d)) * 2048 + s] = f2bf(v);
        } else {
          ((float*)Cout)[(size_t)mrow * 1024 + ncol] = v;
        }
      }
}

// ---------- fused causal attention v4 ----------
// = v2 structure (diagonal pairing + no-max softmax + register K-prefetch pipeline)
//   with NORMAL stores only (NT stores removed: suspected L2-stale-line interaction
//   with the harness's post-validation poison fill across graph replays).
// grid = (16, B*H); block = 256 (4 waves). Block pr handles q-tiles {pr, 31-pr}.

DEV void load_k8(short8 kf[8], const unsigned short* Kp, int jbase, int l15, int l4) {
#pragma unroll
  for (int jb = 0; jb < 4; ++jb) {
    const char* krow = (const char*)(Kp + (size_t)(jbase + jb * 16 + l15) * 1024);
    kf[jb * 2]     = *(const short8*)(krow + (l4 * 8) * 2);
    kf[jb * 2 + 1] = *(const short8*)(krow + (32 + l4 * 8) * 2);
  }
}

DEV void passA_acc(const short8 kf[8], const short8 qf[2], int jbase, bool diag,
                   int myq, int l4, float lacc[4]) {
#pragma unroll
  for (int jb = 0; jb < 4; ++jb) {
    f32x4 a = {};
    a = MFMA16(kf[jb * 2], qf[0], a);
    a = MFMA16(kf[jb * 2 + 1], qf[1], a);
#pragma unroll
    for (int r = 0; r < 4; ++r) {
      int j = jbase + jb * 16 + l4 * 4 + r;
      float e = EXP2F(a[r] * (0.125f * LOG2E));
      lacc[r] += (diag && j > myq) ? 0.f : e;   // 4 independent chains
    }
  }
}

DEV void passB_tile(const short8 kf[8], const short8 qf[2], const unsigned short* Vp,
                    float* Ap, char* pbase, f32x4 oacc[4],
                    int jbase, bool diag, int myq, int l15, int l4, float inv_l) {
  // issue V loads early (consumed only at the end of this iteration)
  short8 vf[8];
#pragma unroll
  for (int db = 0; db < 4; ++db) {
    const char* vrow = (const char*)(Vp + (size_t)(db * 16 + l15) * 2048);
    vf[db * 2]     = *(const short8*)(vrow + (jbase + l4 * 8) * 2);
    vf[db * 2 + 1] = *(const short8*)(vrow + (jbase + 32 + l4 * 8) * 2);
  }
  float p[16];
#pragma unroll
  for (int jb = 0; jb < 4; ++jb) {
    f32x4 a = {};
    a = MFMA16(kf[jb * 2], qf[0], a);
    a = MFMA16(kf[jb * 2 + 1], qf[1], a);
#pragma unroll
    for (int r = 0; r < 4; ++r) {
      int j = jbase + jb * 16 + l4 * 4 + r;
      float e = EXP2F(a[r] * (0.125f * LOG2E)) * inv_l;
      p[jb * 4 + r] = (diag && j > myq) ? 0.f : e;
    }
  }
  // normalized attn write (fp32, regular stores)
#pragma unroll
  for (int jb = 0; jb < 4; ++jb) {
    f32x4 pv = {p[jb * 4], p[jb * 4 + 1], p[jb * 4 + 2], p[jb * 4 + 3]};
    *(f32x4*)(Ap + (size_t)myq * 2048 + jbase + jb * 16 + l4 * 4) = pv;
  }
  // P -> LDS (bf16, per-wave private, padded stride 144B)
#pragma unroll
  for (int jb = 0; jb < 4; ++jb) {
    unsigned u0 = f2bf(p[jb * 4]) | ((unsigned)f2bf(p[jb * 4 + 1]) << 16);
    unsigned u1 = f2bf(p[jb * 4 + 2]) | ((unsigned)f2bf(p[jb * 4 + 3]) << 16);
    uint2 uu; uu.x = u0; uu.y = u1;
    *(uint2*)(pbase + l15 * 144 + (jb * 16 + l4 * 4) * 2) = uu;
  }
  short8 pa0 = *(const short8*)(pbase + l15 * 144 + (l4 * 8) * 2);
  short8 pa1 = *(const short8*)(pbase + l15 * 144 + 64 + (l4 * 8) * 2);
#pragma unroll
  for (int db = 0; db < 4; ++db) {
    oacc[db] = MFMA16(pa0, vf[db * 2], oacc[db]);
    oacc[db] = MFMA16(pa1, vf[db * 2 + 1], oacc[db]);
  }
}

__global__ __launch_bounds__(256) void attn_fused(const unsigned short* __restrict__ Q,
                                                  const unsigned short* __restrict__ Kb,
                                                  const unsigned short* __restrict__ Vt,
                                                  float* __restrict__ attn,
                                                  unsigned short* __restrict__ O) {
  __shared__ unsigned short P_lds[4][16][72];
  const int tid = threadIdx.x, lane = tid & 63, w = tid >> 6;
  const int l15 = lane & 15, l4 = lane >> 4;
  const int pr = blockIdx.x;              // 0..15
  const int bh = blockIdx.y;
  const int b = bh >> 4, h = bh & 15;

  const size_t qk_base = ((size_t)b * 2048) * 1024 + h * 64;
  const unsigned short* Qp = Q + qk_base;
  const unsigned short* Kp = Kb + qk_base;
  const unsigned short* Vbase = Vt + (size_t)bh * 64 * 2048;
  float* Abase = attn + (size_t)bh * 2048 * 2048;
  char* pbase = (char*)&P_lds[w][0][0];

  for (int t = 0; t < 2; ++t) {
    const int qt = t ? (31 - pr) : pr;
    const int q0 = qt * 64 + w * 16;
    const int myq = q0 + l15;
    const int nj = qt + 1;

    short8 qf[2];
    {
      const char* qrow = (const char*)(Qp + (size_t)(q0 + l15) * 1024);
      qf[0] = *(const short8*)(qrow + (l4 * 8) * 2);
      qf[1] = *(const short8*)(qrow + (32 + l4 * 8) * 2);
    }

    // ---- PASS A: sum of exp(s) (no max; 2x-unrolled K prefetch pipeline) ----
    float lacc[4] = {0.f, 0.f, 0.f, 0.f};
    {
      short8 kA[8], kB[8];
      load_k8(kA, Kp, 0, l15, l4);
      int jt = 0;
      while (true) {
        if (jt + 1 < nj) load_k8(kB, Kp, (jt + 1) * 64, l15, l4);
        passA_acc(kA, qf, jt * 64, jt == qt, myq, l4, lacc);
        if (++jt >= nj) break;
        if (jt + 1 < nj) load_k8(kA, Kp, (jt + 1) * 64, l15, l4);
        passA_acc(kB, qf, jt * 64, jt == qt, myq, l4, lacc);
        if (++jt >= nj) break;
      }
    }
    float lsum = (lacc[0] + lacc[1]) + (lacc[2] + lacc[3]);
    lsum += __shfl_xor(lsum, 16);
    lsum += __shfl_xor(lsum, 32);
    const float inv_l = 1.f / lsum;

    // ---- PASS B: write normalized attn + PV ----
    f32x4 oacc[4] = {};
    {
      short8 kA[8], kB[8];
      load_k8(kA, Kp, 0, l15, l4);
      int jt = 0;
      while (true) {
        if (jt + 1 < nj) load_k8(kB, Kp, (jt + 1) * 64, l15, l4);
        passB_tile(kA, qf, Vbase, Abase, pbase, oacc, jt * 64, jt == qt, myq, l15, l4, inv_l);
        if (++jt >= nj) break;
        if (jt + 1 < nj) load_k8(kA, Kp, (jt + 1) * 64, l15, l4);
        passB_tile(kB, qf, Vbase, Abase, pbase, oacc, jt * 64, jt == qt, myq, l15, l4, inv_l);
        if (++jt >= nj) break;
      }
    }

    // zero-fill fully-masked tiles (regular stores)
    for (int jt = nj; jt < 32; ++jt) {
      const int jbase = jt * 64;
      f32x4 z = {};
#pragma unroll
      for (int jb = 0; jb < 4; ++jb)
        *(f32x4*)(Abase + (size_t)myq * 2048 + jbase + jb * 16 + l4 * 4) = z;
    }

    // write O (bf16): D layout row q=(l4*4+r), col d=db*16+l15
#pragma unroll
    for (int db = 0; db < 4; ++db)
#pragma unroll
      for (int r = 0; r < 4; ++r) {
        int q = q0 + l4 * 4 + r;
        int d = db * 16 + l15;
        O[((size_t)b * 2048 + q) * 1024 + h * 64 + d] = f2bf(oacc[db][r]);
      }
  }
}

// ---------- launch ----------
extern "C" void kernel_launch(void* const* d_in, const int* in_sizes, int n_in,
                              void* d_out, int out_size, void* d_ws, size_t ws_size,
                              hipStream_t stream) {
  const float* x  = (const float*)d_in[0];
  // d_in[1] = mask (causal, recomputed analytically)
  const float* wq = (const float*)d_in[2];
  const float* wk = (const float*)d_in[3];
  const float* wv = (const float*)d_in[4];
  const float* wo = (const float*)d_in[5];

  float* out  = (float*)d_out;
  float* attn = out + (size_t)8192 * 1024;

  char* ws = (char*)d_ws;
  const size_t MB = 1 << 20;
  unsigned short* xb  = (unsigned short*)(ws);
  unsigned short* wqb = (unsigned short*)(ws + 16 * MB);
  unsigned short* wkb = (unsigned short*)(ws + 18 * MB);
  unsigned short* wvb = (unsigned short*)(ws + 20 * MB);
  unsigned short* wob = (unsigned short*)(ws + 22 * MB);
  unsigned short* Qb  = (unsigned short*)(ws + 24 * MB);
  unsigned short* Kb  = (unsigned short*)(ws + 40 * MB);
  unsigned short* Vtb = (unsigned short*)(ws + 56 * MB);
  unsigned short* Ob  = (unsigned short*)(ws + 72 * MB);

  // conversions
  cvt_f32_bf16<<<2048, 256, 0, stream>>>(x, xb, 8192 * 1024 / 4);
  cvt_f32_bf16<<<1024, 256, 0, stream>>>(wq, wqb, 1024 * 1024 / 4);
  cvt_f32_bf16<<<1024, 256, 0, stream>>>(wk, wkb, 1024 * 1024 / 4);
  cvt_f32_bf16<<<1024, 256, 0, stream>>>(wv, wvb, 1024 * 1024 / 4);
  cvt_f32_bf16<<<1024, 256, 0, stream>>>(wo, wob, 1024 * 1024 / 4);

  dim3 ggrid(8, 64);   // N/128, M/128
  gemm_bt<0><<<ggrid, 256, 0, stream>>>(xb, wqb, Qb);
  gemm_bt<0><<<ggrid, 256, 0, stream>>>(xb, wkb, Kb);
  gemm_bt<1><<<ggrid, 256, 0, stream>>>(xb, wvb, Vtb);

  attn_fused<<<dim3(16, 64), 256, 0, stream>>>(Qb, Kb, Vtb, attn, Ob);

  gemm_bt<2><<<ggrid, 256, 0, stream>>>(Ob, wob, out);
}